// Round 11
// baseline (216.155 us; speedup 1.0000x reference)
//
#include <hip/hip_runtime.h>
#include <cstdint>
#include <cstddef>

typedef __attribute__((ext_vector_type(8))) short short8;
typedef __attribute__((ext_vector_type(4))) float f32x4;

#define B_ROWS 65536
#define DMODEL 2048
#define NEXP 64
#define TOPK 8
#define THREADS 256                      // 4 waves; wave = 16 rows x 64 experts
#define ROWS_PER_BLK 64
#define NBLK (B_ROWS / ROWS_PER_BLK)     // 1024 blocks = 4 per CU
#define NKS (DMODEL / 32)                // 64 k-steps
#define SLAB 67                          // epilogue slab stride (bank-spread)
#define GOFF ((size_t)B_ROWS * NEXP)
#define AUX_OFF (GOFF + (size_t)B_ROWS * TOPK)
#define WS_FRAG_OFF 131072               // float offset of W-frag region in ws

#define GLOAD16(g, l)                                                      \
  __builtin_amdgcn_global_load_lds(                                       \
      (const __attribute__((address_space(1))) void*)(g),                 \
      (__attribute__((address_space(3))) void*)(l), 16, 0, 0)

// R9-proven RNE bf16 helper: round-to-nearest-even + reconstructed float
__device__ __forceinline__ unsigned short bf16_rne(float v, float* back) {
  unsigned u = __float_as_uint(v);
  unsigned r = (u + 0x7FFFu + ((u >> 16) & 1u)) >> 16;
  *back = __uint_as_float(r << 16);
  return (unsigned short)r;
}

// W -> bf16x3 B-fragments for mfma_f32_16x16x32_bf16.  (R9 numerics verbatim)
// ks-block = 12KB: fragid f = nt*3+term, 512 shorts each; lane l holds 8
// contig bf16 at l*8: B[k = ks*32+(l>>4)*8+j][col = nt*16+(l&15)].
__global__ __launch_bounds__(256) void router_prep(
    const float* __restrict__ W, unsigned short* __restrict__ frag)
{
  const int ks = blockIdx.x;             // 0..63
  const int nt = threadIdx.x >> 6;
  const int lane = threadIdx.x & 63;
  const int krow = ks * 32 + (lane >> 4) * 8;
  const int col = nt * 16 + (lane & 15);
  short8 hv, mv, lv;
#pragma unroll
  for (int j = 0; j < 8; ++j) {
    float v = W[(size_t)(krow + j) * NEXP + col];
    float fh, fm, fl;
    unsigned short h = bf16_rne(v, &fh);
    float r = v - fh;
    unsigned short m = bf16_rne(r, &fm);
    float r2 = r - fm;
    unsigned short l = bf16_rne(r2, &fl);
    hv[j] = (short)h; mv[j] = (short)m; lv[j] = (short)l;
  }
  size_t base = (size_t)(ks * 4 + nt) * 1536 + lane * 8;
  *(short8*)(frag + base)        = hv;
  *(short8*)(frag + base + 512)  = mv;
  *(short8*)(frag + base + 1024) = lv;
}

// R9 cvt3 verbatim (RNE 3-way split)
__device__ __forceinline__ void cvt3(float4 a, float4 b,
                                     short8* H, short8* M, short8* L) {
  float f[8] = {a.x, a.y, a.z, a.w, b.x, b.y, b.z, b.w};
#pragma unroll
  for (int j = 0; j < 8; ++j) {
    float fh, fm, fl;
    unsigned short h = bf16_rne(f[j], &fh);
    float r = f[j] - fh;
    unsigned short m = bf16_rne(r, &fm);
    float r2 = r - fm;
    unsigned short l = bf16_rne(r2, &fl);
    (*H)[j] = (short)h; (*M)[j] = (short)m; (*L)[j] = (short)l;
  }
}

#define MFMA __builtin_amdgcn_mfma_f32_16x16x32_bf16

__global__ __launch_bounds__(THREADS, 4) void router_main(
    const float* __restrict__ x, const float* __restrict__ bias,
    const unsigned short* __restrict__ frag, float* __restrict__ out,
    float* __restrict__ ws)
{
  // LDS union: loop = B double-buffer 2 x 3072 floats (24KB).
  // epilogue slab [64][67] = 4288 floats overlays it (barrier-separated).
  __shared__ __align__(16) float lds[6144];

  const int tid = threadIdx.x;
  const int lane = tid & 63;
  const int w = tid >> 6;
  const size_t row0 = (size_t)blockIdx.x * ROWS_PER_BLK;

  f32x4 acc[4];
#pragma unroll
  for (int nt = 0; nt < 4; ++nt) acc[nt] = (f32x4){0.f, 0.f, 0.f, 0.f};

  // A-side: lane l -> row (l&15), k-cols (l>>4)*8..+7 (2 float4 per ks)
  const float* xp = x + (row0 + (size_t)w * 16 + (lane & 15)) * DMODEL
                  + (lane >> 4) * 8;

  // B staging: wave w stages fragments w*3..w*3+2 (1KB each) of the 12KB ks-block
#define STAGE(KS, BUF)                                                     \
  do {                                                                     \
    _Pragma("unroll") for (int j = 0; j < 3; ++j)                          \
      GLOAD16(frag + (size_t)(KS) * 6144 + (w * 3 + j) * 512 + lane * 8,   \
              lds + (BUF) * 3072 + (w * 3 + j) * 256);                     \
  } while (0)

  STAGE(0, 0);
  float4 c0 = *(const float4*)(xp);
  float4 c1 = *(const float4*)(xp + 4);

  for (int ks = 0; ks < NKS; ++ks) {
    __syncthreads();                     // B(ks) visible; buf^1 free
    float4 n0, n1;
    if (ks + 1 < NKS) {
      STAGE(ks + 1, (ks + 1) & 1);
      n0 = *(const float4*)(xp + (ks + 1) * 32);
      n1 = *(const float4*)(xp + (ks + 1) * 32 + 4);
    }
    const float* bb = lds + (ks & 1) * 3072;
    short8 B[12];
#pragma unroll
    for (int f = 0; f < 12; ++f)
      B[f] = *(const short8*)(bb + f * 256 + lane * 4);   // conflict-free
    short8 Ah, Am, Al;
    cvt3(c0, c1, &Ah, &Am, &Al);
    // R9 product order per nt: Ah·Bh, Ah·Bm, Am·Bh, Am·Bm, Ah·Bl, Al·Bh
#pragma unroll
    for (int nt = 0; nt < 4; ++nt) {
      acc[nt] = MFMA(Ah, B[nt * 3 + 0], acc[nt], 0, 0, 0);
      acc[nt] = MFMA(Ah, B[nt * 3 + 1], acc[nt], 0, 0, 0);
      acc[nt] = MFMA(Am, B[nt * 3 + 0], acc[nt], 0, 0, 0);
      acc[nt] = MFMA(Am, B[nt * 3 + 1], acc[nt], 0, 0, 0);
      acc[nt] = MFMA(Ah, B[nt * 3 + 2], acc[nt], 0, 0, 0);
      acc[nt] = MFMA(Al, B[nt * 3 + 0], acc[nt], 0, 0, 0);
    }
    if (ks + 1 < NKS) { c0 = n0; c1 = n1; }
  }

  // D-frag -> slab[row][expert]: col = lane&15, row = w*16+(lane>>4)*4+reg
  __syncthreads();                       // staging dead; slab live
  float* slab = lds;
#pragma unroll
  for (int nt = 0; nt < 4; ++nt)
#pragma unroll
    for (int reg = 0; reg < 4; ++reg) {
      int row = w * 16 + (lane >> 4) * 4 + reg;
      int col = nt * 16 + (lane & 15);
      slab[row * SLAB + col] = acc[nt][reg];
    }
  __syncthreads();

  // ---------------- epilogue: wave 0, lane = row ----------------
  if (w == 0) {
    float a[NEXP];
#pragma unroll
    for (int n = 0; n < NEXP; ++n) a[n] = slab[lane * SLAB + n];

    // top-8 by biased logits; strict > keeps lowest index on ties
    unsigned long long sel = 0ull;
    int idx[TOPK];
    float selu[TOPK];
#pragma unroll
    for (int k = 0; k < TOPK; ++k) {
      float best = -INFINITY, bestu = 0.f;
      int bi = 0;
#pragma unroll
      for (int n = 0; n < NEXP; ++n) {
        float vb = a[n] + bias[n];
        bool taken = (sel >> n) & 1ull;
        vb = taken ? -INFINITY : vb;
        if (vb > best) { best = vb; bestu = a[n]; bi = n; }
      }
      sel |= 1ull << bi;
      idx[k] = bi;
      selu[k] = bestu;
    }

    float mx = selu[0];
#pragma unroll
    for (int k = 1; k < TOPK; ++k) mx = fmaxf(mx, selu[k]);
    float g[TOPK]; float gs = 0.f;
#pragma unroll
    for (int k = 0; k < TOPK; ++k) { g[k] = __expf(selu[k] - mx); gs += g[k]; }
    float ginv = 1.f / gs;

    float* grow = out + (row0 + lane) * NEXP;
#pragma unroll
    for (int n4 = 0; n4 < 16; ++n4) {
      float gv[4];
#pragma unroll
      for (int j = 0; j < 4; ++j) {
        int n = n4 * 4 + j;
        float v = 0.f;
#pragma unroll
        for (int k = 0; k < TOPK; ++k) v = (idx[k] == n) ? g[k] * ginv : v;
        gv[j] = v;
      }
      *(float4*)(grow + n4 * 4) = make_float4(gv[0], gv[1], gv[2], gv[3]);
    }

    float* irow = out + GOFF + (row0 + lane) * TOPK;
    *(float4*)(irow + 0) = make_float4((float)idx[0], (float)idx[1], (float)idx[2], (float)idx[3]);
    *(float4*)(irow + 4) = make_float4((float)idx[4], (float)idx[5], (float)idx[6], (float)idx[7]);

    // P_i softmax over all 64 logits; F_i via ballot
    float m2 = -INFINITY;
#pragma unroll
    for (int n = 0; n < NEXP; ++n) m2 = fmaxf(m2, a[n]);
    float s2 = 0.f;
#pragma unroll
    for (int n = 0; n < NEXP; ++n) s2 += __expf(a[n] - m2);
    float pinv = 1.f / s2;

    float myP = 0.f, myF = 0.f;
#pragma unroll
    for (int n = 0; n < NEXP; ++n) {
      float v = __expf(a[n] - m2) * pinv;
      v += __shfl_xor(v, 1);
      v += __shfl_xor(v, 2);
      v += __shfl_xor(v, 4);
      v += __shfl_xor(v, 8);
      v += __shfl_xor(v, 16);
      v += __shfl_xor(v, 32);
      unsigned long long b = __ballot((sel >> n) & 1ull);
      if (lane == n) { myP = v; myF = (float)__popcll(b); }
    }
    ws[(size_t)blockIdx.x * (2 * NEXP) + lane] = myF;
    ws[(size_t)blockIdx.x * (2 * NEXP) + NEXP + lane] = myP;
  }
}

// deterministic final reduction over the 1024 block partials
__global__ __launch_bounds__(256) void router_aux(
    const float* __restrict__ ws, float* __restrict__ out)
{
  __shared__ float sf[4][NEXP];
  __shared__ float sp[4][NEXP];
  int t = threadIdx.x;
  int n = t & 63, part = t >> 6;
  float f = 0.f, p = 0.f;
#pragma unroll 8
  for (int b = part; b < NBLK; b += 4) {
    f += ws[(size_t)b * (2 * NEXP) + n];
    p += ws[(size_t)b * (2 * NEXP) + NEXP + n];
  }
  sf[part][n] = f;
  sp[part][n] = p;
  __syncthreads();
  if (t < NEXP) {
    float F = sf[0][t] + sf[1][t] + sf[2][t] + sf[3][t];
    float P = sp[0][t] + sp[1][t] + sp[2][t] + sp[3][t];
    float v = F * P;
    v += __shfl_xor(v, 1);
    v += __shfl_xor(v, 2);
    v += __shfl_xor(v, 4);
    v += __shfl_xor(v, 8);
    v += __shfl_xor(v, 16);
    v += __shfl_xor(v, 32);
    if (t == 0)
      out[AUX_OFF] = 0.01f * 64.f * v / (4294967296.0f /* 65536^2 */);
  }
}

extern "C" void kernel_launch(void* const* d_in, const int* in_sizes, int n_in,
                              void* d_out, int out_size, void* d_ws, size_t ws_size,
                              hipStream_t stream) {
  const float* x = (const float*)d_in[0];
  const float* W = (const float*)d_in[1];
  const float* bias = (const float*)d_in[2];
  float* out = (float*)d_out;
  float* ws = (float*)d_ws;
  unsigned short* frag = (unsigned short*)(ws + WS_FRAG_OFF);
  router_prep<<<NKS, 256, 0, stream>>>(W, frag);
  router_main<<<NBLK, THREADS, 0, stream>>>(x, bias, frag, out, ws);
  router_aux<<<1, 256, 0, stream>>>(ws, out);
}